// Round 3
// baseline (811.752 us; speedup 1.0000x reference)
//
#include <hip/hip_runtime.h>
#include <math.h>

#define B_   16
#define CI   2048
#define NI   16
#define CJ   64
#define NJ   32
#define JM   2048      // CJ*NJ
#define CH   8         // i's per block
#define NBLK 256       // i-chunks = CI/CH
#define ALPHA 8.0f

// ---------------------------------------------------------------------------
// Pass kernel. 1024 threads: bh = tid>>8 in {0..3} -> b = bh*4+bb (bb 0..3)
// jg = tid&255 -> jm0 = jg*8 (8 contiguous jm per thread, quarter of one j)
// Each block handles CH=8 consecutive i's, all 16 b, all 2048 jm.
// Per-thread live state at the softmax barrier: u[4][8]+acc[4][8]+L[4] ~ 85
// floats -> fits in 128 VGPRs. amdgpu_waves_per_eu(4,4) pins the allocator
// to exactly 4 waves/EU (1024-thr block = 1 block/CU) so it uses the full
// 128-VGPR budget instead of spilling to hit 8 waves/EU (R2: VGPR=64 +
// ~180MB/pass scratch traffic).
// PASS 0: acc += u
// PASS 1: a0 = sum_m v0*u (stored), c = softmax(8*a0)*64, acc += c*u
// PASS 2: L = a0 + sum_m v1*u, c = softmax(8*L)*64, acc += c*u
// ---------------------------------------------------------------------------
template <int PASS, bool ATOMIC>
__global__ __launch_bounds__(1024)
__attribute__((amdgpu_waves_per_eu(4, 4)))
void pass_kernel(const float* __restrict__ x, const float* __restrict__ w,
                 const float* __restrict__ vprev, float* __restrict__ a0,
                 float* __restrict__ sout)
{
    __shared__ float xs[CH][B_][NI];   // 8 KB staged inputs
    __shared__ float Ls[B_][CJ];       // 4 KB logits for softmax
    __shared__ float smax[B_], sinv[B_];

    const int tid  = threadIdx.x;
    const int bh   = tid >> 8;        // 0..3
    const int jg   = tid & 255;
    const int jm0  = jg * 8;
    const int jcol = jg >> 2;         // j in 0..63 (4 lanes per j)
    const int i0   = blockIdx.x * CH;

    // stage x[b, i0..i0+7, :] into LDS (512 aligned float4 loads)
    if (tid < 512) {
        const int f    = tid * 4;
        const int n    = f & 15;
        const int bidx = (f >> 4) & 15;
        const int ci   = f >> 8;
        *(float4*)(&xs[ci][bidx][n]) =
            *(const float4*)(x + (size_t)bidx * (CI * NI)
                               + (size_t)(i0 + ci) * NI + n);
    }

    float acc[4][8];
#pragma unroll
    for (int bb = 0; bb < 4; ++bb)
#pragma unroll
        for (int k = 0; k < 8; ++k) acc[bb][k] = 0.0f;

    __syncthreads();

    for (int ci = 0; ci < CH; ++ci) {
        const int i = i0 + ci;

        // ---- recompute u[b, i, jm0..jm0+7] for b = bh*4 .. bh*4+3 ----
        float u[4][8];
#pragma unroll
        for (int bb = 0; bb < 4; ++bb)
#pragma unroll
            for (int k = 0; k < 8; ++k) u[bb][k] = 0.0f;

        const float* wrow = w + (size_t)i * (NI * JM) + jm0;
#pragma unroll
        for (int n = 0; n < NI; ++n) {
            const float4 w0 = *(const float4*)(wrow + (size_t)n * JM);
            const float4 w1 = *(const float4*)(wrow + (size_t)n * JM + 4);
#pragma unroll
            for (int bb = 0; bb < 4; ++bb) {
                const float xv = xs[ci][bh * 4 + bb][n];
                u[bb][0] = fmaf(xv, w0.x, u[bb][0]);
                u[bb][1] = fmaf(xv, w0.y, u[bb][1]);
                u[bb][2] = fmaf(xv, w0.z, u[bb][2]);
                u[bb][3] = fmaf(xv, w0.w, u[bb][3]);
                u[bb][4] = fmaf(xv, w1.x, u[bb][4]);
                u[bb][5] = fmaf(xv, w1.y, u[bb][5]);
                u[bb][6] = fmaf(xv, w1.z, u[bb][6]);
                u[bb][7] = fmaf(xv, w1.w, u[bb][7]);
            }
        }

        if (PASS == 0) {
#pragma unroll
            for (int bb = 0; bb < 4; ++bb)
#pragma unroll
                for (int k = 0; k < 8; ++k) acc[bb][k] += u[bb][k];
        } else {
            // ---- agreement: ap[b,j] = sum_m vprev[b,j,m]*u[b,i,j,m] ----
            float ap[4];
#pragma unroll
            for (int bb = 0; bb < 4; ++bb) {
                const int b = bh * 4 + bb;
                const float4 v0 = *(const float4*)(vprev + b * JM + jm0);
                const float4 v1 = *(const float4*)(vprev + b * JM + jm0 + 4);
                float t = u[bb][0] * v0.x + u[bb][1] * v0.y
                        + u[bb][2] * v0.z + u[bb][3] * v0.w
                        + u[bb][4] * v1.x + u[bb][5] * v1.y
                        + u[bb][6] * v1.z + u[bb][7] * v1.w;
                // 4 lanes share one (b,j): butterfly over the quad
                t += __shfl_xor(t, 1);
                t += __shfl_xor(t, 2);
                ap[bb] = t;
            }

            // logits
            float L[4];
#pragma unroll
            for (int bb = 0; bb < 4; ++bb) {
                if (PASS == 1) {
                    L[bb] = ap[bb];
                } else {
                    const int b = bh * 4 + bb;
                    L[bb] = ap[bb] + a0[((size_t)b * CI + i) * CJ + jcol];
                }
            }
            if ((jg & 3) == 0) {
#pragma unroll
                for (int bb = 0; bb < 4; ++bb) {
                    const int b = bh * 4 + bb;
                    Ls[b][jcol] = L[bb];
                    if (PASS == 1)
                        a0[((size_t)b * CI + i) * CJ + jcol] = ap[bb];
                }
            }
            __syncthreads();

            // softmax over j (64 values per b); threads 0..511: (rb, rj)
            if (tid < 512) {
                const int rb = tid >> 5, rj = tid & 31;
                const float x1 = Ls[rb][rj];
                const float x2 = Ls[rb][rj + 32];
                float mx = fmaxf(x1, x2);
#pragma unroll
                for (int s2 = 1; s2 < 32; s2 <<= 1)
                    mx = fmaxf(mx, __shfl_xor(mx, s2));
                float ex = __expf(ALPHA * (x1 - mx)) + __expf(ALPHA * (x2 - mx));
#pragma unroll
                for (int s2 = 1; s2 < 32; s2 <<= 1)
                    ex += __shfl_xor(ex, s2);
                if (rj == 0) { smax[rb] = mx; sinv[rb] = 64.0f / ex; }
            }
            __syncthreads();

            // c = softmax(8*L)*64 ; acc += c*u
#pragma unroll
            for (int bb = 0; bb < 4; ++bb) {
                const int b = bh * 4 + bb;
                const float c = __expf(ALPHA * (L[bb] - smax[b])) * sinv[b];
#pragma unroll
                for (int k = 0; k < 8; ++k)
                    acc[bb][k] = fmaf(c, u[bb][k], acc[bb][k]);
            }
        }
    }

    if (ATOMIC) {
#pragma unroll
        for (int bb = 0; bb < 4; ++bb) {
            const int b = bh * 4 + bb;
#pragma unroll
            for (int k = 0; k < 8; ++k)
                unsafeAtomicAdd(sout + b * JM + jm0 + k, acc[bb][k]);
        }
    } else {
        float* dst = sout + (size_t)blockIdx.x * (B_ * JM);
#pragma unroll
        for (int bb = 0; bb < 4; ++bb) {
            const int b = bh * 4 + bb;
            *(float4*)(dst + b * JM + jm0)     =
                make_float4(acc[bb][0], acc[bb][1], acc[bb][2], acc[bb][3]);
            *(float4*)(dst + b * JM + jm0 + 4) =
                make_float4(acc[bb][4], acc[bb][5], acc[bb][6], acc[bb][7]);
        }
    }
}

// ---------------------------------------------------------------------------
// reduce 256 partials + squash, split-K parallel version.
// grid 256 blocks x 1024 threads. Block r handles 128 consecutive outputs
// (= 4 full j-rows of 32 m). tid = seg(8) x loc(128): seg sums 32 partials,
// LDS combine, then tid<128 do the 32-m squash via in-wave shuffle.
// ---------------------------------------------------------------------------
__global__ __launch_bounds__(1024)
void reduce_squash(const float* __restrict__ part, float* __restrict__ v)
{
    __shared__ float red[8][128];
    const int tid = threadIdx.x;
    const int seg = tid >> 7;          // 0..7
    const int loc = tid & 127;         // 0..127
    const int g   = blockIdx.x * 128 + loc;

    float s0 = 0.f, s1 = 0.f, s2 = 0.f, s3 = 0.f;
    const float* p = part + (size_t)(seg * 32) * (B_ * JM) + g;
#pragma unroll 8
    for (int q = 0; q < 32; q += 4) {
        s0 += p[(size_t)(q + 0) * (B_ * JM)];
        s1 += p[(size_t)(q + 1) * (B_ * JM)];
        s2 += p[(size_t)(q + 2) * (B_ * JM)];
        s3 += p[(size_t)(q + 3) * (B_ * JM)];
    }
    red[seg][loc] = (s0 + s1) + (s2 + s3);
    __syncthreads();

    if (tid < 128) {
        float s = 0.f;
#pragma unroll
        for (int q = 0; q < 8; ++q) s += red[q][loc];
        float sq = s * s;
#pragma unroll
        for (int k = 1; k < 32; k <<= 1) sq += __shfl_xor(sq, k);
        v[g] = (sq / (1.0f + sq)) * (s * rsqrtf(sq + 1e-7f));
    }
}

// fallback squash (atomic path)
__global__ __launch_bounds__(256)
void squash_kernel(const float* __restrict__ s, float* __restrict__ v)
{
    const int g = blockIdx.x * 256 + threadIdx.x;
    const float val = s[g];
    float sq = val * val;
#pragma unroll
    for (int k = 1; k < 32; k <<= 1) sq += __shfl_xor(sq, k);
    v[g] = (sq / (1.0f + sq)) * (val * rsqrtf(sq + 1e-7f));
}

// ---------------------------------------------------------------------------
extern "C" void kernel_launch(void* const* d_in, const int* in_sizes, int n_in,
                              void* d_out, int out_size, void* d_ws, size_t ws_size,
                              hipStream_t stream)
{
    const float* x = (const float*)d_in[0];
    const float* w = (const float*)d_in[1];
    float* out = (float*)d_out;
    float* ws  = (float*)d_ws;

    float* A0   = ws;                                   // 16*2048*64 = 2,097,152
    float* V0   = A0 + (size_t)B_ * CI * CJ;            // 32768
    float* V1   = V0 + B_ * JM;                         // 32768
    float* PART = V1 + B_ * JM;                         // 256*16*2048 = 8,388,608
    const size_t need_part =
        ((size_t)B_ * CI * CJ + 2 * (size_t)B_ * JM
         + (size_t)NBLK * B_ * JM) * sizeof(float);     // ~42.6 MB

    if (ws_size >= need_part) {
        pass_kernel<0, false><<<NBLK, 1024, 0, stream>>>(x, w, nullptr, nullptr, PART);
        reduce_squash<<<256, 1024, 0, stream>>>(PART, V0);
        pass_kernel<1, false><<<NBLK, 1024, 0, stream>>>(x, w, V0, A0, PART);
        reduce_squash<<<256, 1024, 0, stream>>>(PART, V1);
        pass_kernel<2, false><<<NBLK, 1024, 0, stream>>>(x, w, V1, A0, PART);
        reduce_squash<<<256, 1024, 0, stream>>>(PART, out);
    } else {
        // fallback: atomic accumulation
        float* S0 = V1 + B_ * JM;
        float* S1 = S0 + B_ * JM;
        float* S2 = S1 + B_ * JM;
        hipMemsetAsync(S0, 0, (size_t)3 * B_ * JM * sizeof(float), stream);
        pass_kernel<0, true><<<NBLK, 1024, 0, stream>>>(x, w, nullptr, nullptr, S0);
        squash_kernel<<<128, 256, 0, stream>>>(S0, V0);
        pass_kernel<1, true><<<NBLK, 1024, 0, stream>>>(x, w, V0, A0, S1);
        squash_kernel<<<128, 256, 0, stream>>>(S1, V1);
        pass_kernel<2, true><<<NBLK, 1024, 0, stream>>>(x, w, V1, A0, S2);
        squash_kernel<<<128, 256, 0, stream>>>(S2, out);
    }
}

// Round 4
// 755.806 us; speedup vs baseline: 1.0740x; 1.0740x over previous
//
#include <hip/hip_runtime.h>
#include <math.h>

#define B_   16
#define CI   2048
#define NI   16
#define CJ   64
#define NJ   32
#define JM   2048      // CJ*NJ
#define CH   8         // i's per block
#define NCH  256       // i-chunks = CI/CH
#define ALPHA 8.0f

// ---------------------------------------------------------------------------
// Pass kernel, b-split: 512 blocks = (ichunk 0..255) x (bhalf 0..1).
// XCD swizzle: idx -> xcd=idx&7, bhalf=(idx>>3)&1, slot=idx>>4,
// ichunk=slot*8+xcd. Siblings (same ichunk, both bhalves) are idx and idx+8:
// same XCD (round-robin %8) -> shared L2 for the duplicated w-row reads.
// 1024 threads: bh=tid>>8 (0..3), bb in {0,1} -> local bg=bh*2+bb (8 b's),
// jg=tid&255 -> jm0=jg*8. Per-thread state u[2][8]+acc[2][8] ~ 55 VGPRs:
// fits the allocator's 64-VGPR / 8-waves-per-EU target with ZERO spill
// (R2/R3 lesson: it will not allocate more than 64 for this shape).
// PASS 0: acc += u
// PASS 1: a0 = sum_m v0*u (stored), c = softmax(8*a0)*64, acc += c*u
// PASS 2: L = a0 + sum_m v1*u, c = softmax(8*L)*64, acc += c*u
// Partials: PART[b][ichunk][jm]  (reduce reads 8KB-stride, 1KB rows)
// ---------------------------------------------------------------------------
template <int PASS, bool ATOMIC>
__global__ __launch_bounds__(1024)
void pass_kernel(const float* __restrict__ x, const float* __restrict__ w,
                 const float* __restrict__ vprev, float* __restrict__ a0,
                 float* __restrict__ sout)
{
    __shared__ float xs[CH][8][NI];    // 4 KB staged inputs (8 b's)
    __shared__ float Ls[8][CJ];        // 2 KB logits
    __shared__ float smax[8], sinv[8];

    const int idx    = blockIdx.x;
    const int xcd    = idx & 7;
    const int bhalf  = (idx >> 3) & 1;
    const int slot   = idx >> 4;
    const int ichunk = slot * 8 + xcd;
    const int i0     = ichunk * CH;
    const int b0     = bhalf * 8;

    const int tid  = threadIdx.x;
    const int bh   = tid >> 8;        // 0..3
    const int jg   = tid & 255;
    const int jm0  = jg * 8;
    const int jcol = jg >> 2;         // j in 0..63 (4 lanes per j)

    // stage x[b0..b0+7, i0..i0+7, :] into LDS (256 aligned float4 loads)
    if (tid < 256) {
        const int f  = tid * 4;
        const int n  = f & 15;
        const int bg = (f >> 4) & 7;
        const int ci = f >> 7;
        *(float4*)(&xs[ci][bg][n]) =
            *(const float4*)(x + ((size_t)(b0 + bg) * CI + (i0 + ci)) * NI + n);
    }

    float acc[2][8];
#pragma unroll
    for (int bb = 0; bb < 2; ++bb)
#pragma unroll
        for (int k = 0; k < 8; ++k) acc[bb][k] = 0.0f;

    __syncthreads();

    for (int ci = 0; ci < CH; ++ci) {
        const int i = i0 + ci;

        // ---- recompute u[b, i, jm0..jm0+7] for bg = bh*2, bh*2+1 ----
        float u[2][8];
#pragma unroll
        for (int bb = 0; bb < 2; ++bb)
#pragma unroll
            for (int k = 0; k < 8; ++k) u[bb][k] = 0.0f;

        const float* wrow = w + (size_t)i * (NI * JM) + jm0;
#pragma unroll
        for (int n = 0; n < NI; ++n) {
            const float4 w0 = *(const float4*)(wrow + (size_t)n * JM);
            const float4 w1 = *(const float4*)(wrow + (size_t)n * JM + 4);
#pragma unroll
            for (int bb = 0; bb < 2; ++bb) {
                const float xv = xs[ci][bh * 2 + bb][n];
                u[bb][0] = fmaf(xv, w0.x, u[bb][0]);
                u[bb][1] = fmaf(xv, w0.y, u[bb][1]);
                u[bb][2] = fmaf(xv, w0.z, u[bb][2]);
                u[bb][3] = fmaf(xv, w0.w, u[bb][3]);
                u[bb][4] = fmaf(xv, w1.x, u[bb][4]);
                u[bb][5] = fmaf(xv, w1.y, u[bb][5]);
                u[bb][6] = fmaf(xv, w1.z, u[bb][6]);
                u[bb][7] = fmaf(xv, w1.w, u[bb][7]);
            }
        }

        if (PASS == 0) {
#pragma unroll
            for (int bb = 0; bb < 2; ++bb)
#pragma unroll
                for (int k = 0; k < 8; ++k) acc[bb][k] += u[bb][k];
        } else {
            // ---- agreement: ap[bg,j] = sum_m vprev[b,j,m]*u[b,i,j,m] ----
            float ap[2];
#pragma unroll
            for (int bb = 0; bb < 2; ++bb) {
                const int b = b0 + bh * 2 + bb;
                const float4 v0 = *(const float4*)(vprev + (size_t)b * JM + jm0);
                const float4 v1 = *(const float4*)(vprev + (size_t)b * JM + jm0 + 4);
                float t = u[bb][0] * v0.x + u[bb][1] * v0.y
                        + u[bb][2] * v0.z + u[bb][3] * v0.w
                        + u[bb][4] * v1.x + u[bb][5] * v1.y
                        + u[bb][6] * v1.z + u[bb][7] * v1.w;
                t += __shfl_xor(t, 1);   // 4 lanes share one (b,j)
                t += __shfl_xor(t, 2);
                ap[bb] = t;
            }

            float L[2];
#pragma unroll
            for (int bb = 0; bb < 2; ++bb) {
                if (PASS == 1) {
                    L[bb] = ap[bb];
                } else {
                    const int b = b0 + bh * 2 + bb;
                    L[bb] = ap[bb] + a0[((size_t)b * CI + i) * CJ + jcol];
                }
            }
            if ((jg & 3) == 0) {
#pragma unroll
                for (int bb = 0; bb < 2; ++bb) {
                    const int bg = bh * 2 + bb;
                    Ls[bg][jcol] = L[bb];
                    if (PASS == 1)
                        a0[((size_t)(b0 + bg) * CI + i) * CJ + jcol] = ap[bb];
                }
            }
            __syncthreads();

            // softmax over 64 j for 8 local b; threads 0..255: (rb, rj)
            if (tid < 256) {
                const int rb = tid >> 5, rj = tid & 31;
                const float x1 = Ls[rb][rj];
                const float x2 = Ls[rb][rj + 32];
                float mx = fmaxf(x1, x2);
#pragma unroll
                for (int s2 = 1; s2 < 32; s2 <<= 1)
                    mx = fmaxf(mx, __shfl_xor(mx, s2));
                float ex = __expf(ALPHA * (x1 - mx)) + __expf(ALPHA * (x2 - mx));
#pragma unroll
                for (int s2 = 1; s2 < 32; s2 <<= 1)
                    ex += __shfl_xor(ex, s2);
                if (rj == 0) { smax[rb] = mx; sinv[rb] = 64.0f / ex; }
            }
            __syncthreads();

            // c = softmax(8*L)*64 ; acc += c*u
#pragma unroll
            for (int bb = 0; bb < 2; ++bb) {
                const int bg = bh * 2 + bb;
                const float c = __expf(ALPHA * (L[bb] - smax[bg])) * sinv[bg];
#pragma unroll
                for (int k = 0; k < 8; ++k)
                    acc[bb][k] = fmaf(c, u[bb][k], acc[bb][k]);
            }
        }
    }

    if (ATOMIC) {
#pragma unroll
        for (int bb = 0; bb < 2; ++bb) {
            const int b = b0 + bh * 2 + bb;
#pragma unroll
            for (int k = 0; k < 8; ++k)
                unsafeAtomicAdd(sout + (size_t)b * JM + jm0 + k, acc[bb][k]);
        }
    } else {
        // PART[b][ichunk][jm]
#pragma unroll
        for (int bb = 0; bb < 2; ++bb) {
            const int b = b0 + bh * 2 + bb;
            float* dst = sout + ((size_t)b * NCH + ichunk) * JM + jm0;
            *(float4*)(dst)     =
                make_float4(acc[bb][0], acc[bb][1], acc[bb][2], acc[bb][3]);
            *(float4*)(dst + 4) =
                make_float4(acc[bb][4], acc[bb][5], acc[bb][6], acc[bb][7]);
        }
    }
}

// ---------------------------------------------------------------------------
// reduce PART[b][p][jm] over p (256) + squash.
// grid 128 x 1024. block: b = bid>>3, jmbase = (bid&7)*256.
// thread: seg = tid>>8 (4 segs x 64 p), loc = tid&255 (output within block).
// Reads: 1 KB contiguous rows at 8 KB stride, 16 loads in flight per thread.
// ---------------------------------------------------------------------------
__global__ __launch_bounds__(1024)
void reduce_squash(const float* __restrict__ part, float* __restrict__ v)
{
    __shared__ float red[4][256];
    const int tid = threadIdx.x;
    const int seg = tid >> 8;          // 0..3
    const int loc = tid & 255;         // 0..255
    const int b   = blockIdx.x >> 3;
    const int jmb = (blockIdx.x & 7) * 256;

    const float* p = part + ((size_t)b * NCH + seg * 64) * JM + jmb + loc;
    float s0 = 0.f, s1 = 0.f, s2 = 0.f, s3 = 0.f;
#pragma unroll 4
    for (int q = 0; q < 64; q += 4) {
        s0 += p[(size_t)(q + 0) * JM];
        s1 += p[(size_t)(q + 1) * JM];
        s2 += p[(size_t)(q + 2) * JM];
        s3 += p[(size_t)(q + 3) * JM];
    }
    red[seg][loc] = (s0 + s1) + (s2 + s3);
    __syncthreads();

    if (tid < 256) {
        const float s = (red[0][loc] + red[1][loc]) + (red[2][loc] + red[3][loc]);
        float sq = s * s;
#pragma unroll
        for (int k = 1; k < 32; k <<= 1) sq += __shfl_xor(sq, k);
        v[(size_t)b * JM + jmb + loc] =
            (sq / (1.0f + sq)) * (s * rsqrtf(sq + 1e-7f));
    }
}

// fallback squash (atomic path)
__global__ __launch_bounds__(256)
void squash_kernel(const float* __restrict__ s, float* __restrict__ v)
{
    const int g = blockIdx.x * 256 + threadIdx.x;
    const float val = s[g];
    float sq = val * val;
#pragma unroll
    for (int k = 1; k < 32; k <<= 1) sq += __shfl_xor(sq, k);
    v[g] = (sq / (1.0f + sq)) * (val * rsqrtf(sq + 1e-7f));
}

// ---------------------------------------------------------------------------
extern "C" void kernel_launch(void* const* d_in, const int* in_sizes, int n_in,
                              void* d_out, int out_size, void* d_ws, size_t ws_size,
                              hipStream_t stream)
{
    const float* x = (const float*)d_in[0];
    const float* w = (const float*)d_in[1];
    float* out = (float*)d_out;
    float* ws  = (float*)d_ws;

    float* A0   = ws;                                   // 16*2048*64 = 2,097,152
    float* V0   = A0 + (size_t)B_ * CI * CJ;            // 32768
    float* V1   = V0 + (size_t)B_ * JM;                 // 32768
    float* PART = V1 + (size_t)B_ * JM;                 // 16*256*2048 = 8,388,608
    const size_t need_part =
        ((size_t)B_ * CI * CJ + 2 * (size_t)B_ * JM
         + (size_t)B_ * NCH * JM) * sizeof(float);      // ~42.6 MB

    if (ws_size >= need_part) {
        pass_kernel<0, false><<<512, 1024, 0, stream>>>(x, w, nullptr, nullptr, PART);
        reduce_squash<<<128, 1024, 0, stream>>>(PART, V0);
        pass_kernel<1, false><<<512, 1024, 0, stream>>>(x, w, V0, A0, PART);
        reduce_squash<<<128, 1024, 0, stream>>>(PART, V1);
        pass_kernel<2, false><<<512, 1024, 0, stream>>>(x, w, V1, A0, PART);
        reduce_squash<<<128, 1024, 0, stream>>>(PART, out);
    } else {
        // fallback: atomic accumulation
        float* S0 = V1 + (size_t)B_ * JM;
        float* S1 = S0 + (size_t)B_ * JM;
        float* S2 = S1 + (size_t)B_ * JM;
        hipMemsetAsync(S0, 0, (size_t)3 * B_ * JM * sizeof(float), stream);
        pass_kernel<0, true><<<512, 1024, 0, stream>>>(x, w, nullptr, nullptr, S0);
        squash_kernel<<<128, 256, 0, stream>>>(S0, V0);
        pass_kernel<1, true><<<512, 1024, 0, stream>>>(x, w, V0, A0, S1);
        squash_kernel<<<128, 256, 0, stream>>>(S1, V1);
        pass_kernel<2, true><<<512, 1024, 0, stream>>>(x, w, V1, A0, S2);
        squash_kernel<<<128, 256, 0, stream>>>(S2, out);
    }
}

// Round 5
// 585.624 us; speedup vs baseline: 1.3861x; 1.2906x over previous
//
#include <hip/hip_runtime.h>
#include <hip/hip_fp16.h>
#include <math.h>

#define B_   16
#define CI   2048
#define NI   16
#define CJ   64
#define NJ   32
#define JM   2048      // CJ*NJ
#define CH   8         // i's per block
#define NCH  256       // i-chunks = CI/CH
#define ALPHA 8.0f

// ---------------------------------------------------------------------------
// Pass kernel (R4 structure), b-split: 512 blocks = (ichunk) x (bhalf).
// STOREU: PASS==0 additionally stores u as fp16 to U16[b][i][jm] (coalesced
// 16B per thread) for the route_kernel passes to consume.
// Empirical (R2-R4): this kernel is pinned at ~3.1 TB/s of L2-miss traffic
// regardless of occupancy/VGPRs -> only lever is less far traffic.
// ---------------------------------------------------------------------------
template <int PASS, bool ATOMIC, bool STOREU>
__global__ __launch_bounds__(1024)
void pass_kernel(const float* __restrict__ x, const float* __restrict__ w,
                 const float* __restrict__ vprev, float* __restrict__ a0,
                 float* __restrict__ sout, __half* __restrict__ U16)
{
    __shared__ float xs[CH][8][NI];    // 4 KB staged inputs (8 b's)
    __shared__ float Ls[8][CJ];        // 2 KB logits
    __shared__ float smax[8], sinv[8];

    const int idx    = blockIdx.x;
    const int xcd    = idx & 7;
    const int bhalf  = (idx >> 3) & 1;
    const int slot   = idx >> 4;
    const int ichunk = slot * 8 + xcd;
    const int i0     = ichunk * CH;
    const int b0     = bhalf * 8;

    const int tid  = threadIdx.x;
    const int bh   = tid >> 8;        // 0..3
    const int jg   = tid & 255;
    const int jm0  = jg * 8;
    const int jcol = jg >> 2;         // j in 0..63

    if (tid < 256) {
        const int f  = tid * 4;
        const int n  = f & 15;
        const int bg = (f >> 4) & 7;
        const int ci = f >> 7;
        *(float4*)(&xs[ci][bg][n]) =
            *(const float4*)(x + ((size_t)(b0 + bg) * CI + (i0 + ci)) * NI + n);
    }

    float acc[2][8];
#pragma unroll
    for (int bb = 0; bb < 2; ++bb)
#pragma unroll
        for (int k = 0; k < 8; ++k) acc[bb][k] = 0.0f;

    __syncthreads();

    for (int ci = 0; ci < CH; ++ci) {
        const int i = i0 + ci;

        float u[2][8];
#pragma unroll
        for (int bb = 0; bb < 2; ++bb)
#pragma unroll
            for (int k = 0; k < 8; ++k) u[bb][k] = 0.0f;

        const float* wrow = w + (size_t)i * (NI * JM) + jm0;
#pragma unroll
        for (int n = 0; n < NI; ++n) {
            const float4 w0 = *(const float4*)(wrow + (size_t)n * JM);
            const float4 w1 = *(const float4*)(wrow + (size_t)n * JM + 4);
#pragma unroll
            for (int bb = 0; bb < 2; ++bb) {
                const float xv = xs[ci][bh * 2 + bb][n];
                u[bb][0] = fmaf(xv, w0.x, u[bb][0]);
                u[bb][1] = fmaf(xv, w0.y, u[bb][1]);
                u[bb][2] = fmaf(xv, w0.z, u[bb][2]);
                u[bb][3] = fmaf(xv, w0.w, u[bb][3]);
                u[bb][4] = fmaf(xv, w1.x, u[bb][4]);
                u[bb][5] = fmaf(xv, w1.y, u[bb][5]);
                u[bb][6] = fmaf(xv, w1.z, u[bb][6]);
                u[bb][7] = fmaf(xv, w1.w, u[bb][7]);
            }
        }

        if (PASS == 0) {
#pragma unroll
            for (int bb = 0; bb < 2; ++bb)
#pragma unroll
                for (int k = 0; k < 8; ++k) acc[bb][k] += u[bb][k];
            if (STOREU) {
#pragma unroll
                for (int bb = 0; bb < 2; ++bb) {
                    const int b = b0 + bh * 2 + bb;
                    union { uint4 q; __half h[8]; } pk;
#pragma unroll
                    for (int k = 0; k < 8; ++k) pk.h[k] = __float2half(u[bb][k]);
                    *(uint4*)(U16 + ((size_t)b * CI + i) * JM + jm0) = pk.q;
                }
            }
        } else {
            float ap[2];
#pragma unroll
            for (int bb = 0; bb < 2; ++bb) {
                const int b = b0 + bh * 2 + bb;
                const float4 v0 = *(const float4*)(vprev + (size_t)b * JM + jm0);
                const float4 v1 = *(const float4*)(vprev + (size_t)b * JM + jm0 + 4);
                float t = u[bb][0] * v0.x + u[bb][1] * v0.y
                        + u[bb][2] * v0.z + u[bb][3] * v0.w
                        + u[bb][4] * v1.x + u[bb][5] * v1.y
                        + u[bb][6] * v1.z + u[bb][7] * v1.w;
                t += __shfl_xor(t, 1);
                t += __shfl_xor(t, 2);
                ap[bb] = t;
            }

            float L[2];
#pragma unroll
            for (int bb = 0; bb < 2; ++bb) {
                if (PASS == 1) {
                    L[bb] = ap[bb];
                } else {
                    const int b = b0 + bh * 2 + bb;
                    L[bb] = ap[bb] + a0[((size_t)b * CI + i) * CJ + jcol];
                }
            }
            if ((jg & 3) == 0) {
#pragma unroll
                for (int bb = 0; bb < 2; ++bb) {
                    const int bg = bh * 2 + bb;
                    Ls[bg][jcol] = L[bb];
                    if (PASS == 1)
                        a0[((size_t)(b0 + bg) * CI + i) * CJ + jcol] = ap[bb];
                }
            }
            __syncthreads();

            if (tid < 256) {
                const int rb = tid >> 5, rj = tid & 31;
                const float x1 = Ls[rb][rj];
                const float x2 = Ls[rb][rj + 32];
                float mx = fmaxf(x1, x2);
#pragma unroll
                for (int s2 = 1; s2 < 32; s2 <<= 1)
                    mx = fmaxf(mx, __shfl_xor(mx, s2));
                float ex = __expf(ALPHA * (x1 - mx)) + __expf(ALPHA * (x2 - mx));
#pragma unroll
                for (int s2 = 1; s2 < 32; s2 <<= 1)
                    ex += __shfl_xor(ex, s2);
                if (rj == 0) { smax[rb] = mx; sinv[rb] = 64.0f / ex; }
            }
            __syncthreads();

#pragma unroll
            for (int bb = 0; bb < 2; ++bb) {
                const int bg = bh * 2 + bb;
                const float c = __expf(ALPHA * (L[bb] - smax[bg])) * sinv[bg];
#pragma unroll
                for (int k = 0; k < 8; ++k)
                    acc[bb][k] = fmaf(c, u[bb][k], acc[bb][k]);
            }
        }
    }

    if (ATOMIC) {
#pragma unroll
        for (int bb = 0; bb < 2; ++bb) {
            const int b = b0 + bh * 2 + bb;
#pragma unroll
            for (int k = 0; k < 8; ++k)
                unsafeAtomicAdd(sout + (size_t)b * JM + jm0 + k, acc[bb][k]);
        }
    } else {
#pragma unroll
        for (int bb = 0; bb < 2; ++bb) {
            const int b = b0 + bh * 2 + bb;
            float* dst = sout + ((size_t)b * NCH + ichunk) * JM + jm0;
            *(float4*)(dst)     =
                make_float4(acc[bb][0], acc[bb][1], acc[bb][2], acc[bb][3]);
            *(float4*)(dst + 4) =
                make_float4(acc[bb][4], acc[bb][5], acc[bb][6], acc[bb][7]);
        }
    }
}

// ---------------------------------------------------------------------------
// Routing pass over cached fp16 u — no w reads. Barrier-free main loop:
// one WAVE handles one (b, i): lane l = capsule j (64 lanes = 64 j's),
// holding all 32 m. Softmax over j = 6-step shfl_xor. v staged transposed
// vT[m][j] in LDS (bank = l%32, 2-way alias = free).
// grid: 1024 blocks = b(16) x igroup(64 of 32 i). 256 thr = 4 waves x 8 i.
// PART row per wave: p = ig*4 + wave (256 partials, same reduce kernel).
// PASS 1: a0 = sum_m v0*u (stored), c = softmax(8*a0)*64,      acc += c*u
// PASS 2: L = a0 + sum_m v1*u,      c = softmax(8*L)*64,       acc += c*u
// ---------------------------------------------------------------------------
template <int PASS>
__global__ __launch_bounds__(256)
void route_kernel(const __half* __restrict__ U16, const float* __restrict__ vprev,
                  float* __restrict__ a0, float* __restrict__ part)
{
    __shared__ float vT[32 * 64];   // vT[m][j]

    const int tid = threadIdx.x;
    const int b   = blockIdx.x >> 6;
    const int ig  = blockIdx.x & 63;
    const int wv  = tid >> 6;
    const int l   = tid & 63;       // j = l

    // stage v[b][j][m] -> vT[m][j]
    {
        const float* vp = vprev + (size_t)b * JM + tid * 8;
        const float4 f0 = *(const float4*)(vp);
        const float4 f1 = *(const float4*)(vp + 4);
        const float tmp[8] = {f0.x, f0.y, f0.z, f0.w, f1.x, f1.y, f1.z, f1.w};
#pragma unroll
        for (int k = 0; k < 8; ++k) {
            const int jm = tid * 8 + k;
            vT[(jm & 31) * 64 + (jm >> 5)] = tmp[k];
        }
    }
    __syncthreads();

    float acc[32];
#pragma unroll
    for (int m = 0; m < 32; ++m) acc[m] = 0.0f;

    for (int ii = 0; ii < 8; ++ii) {
        const int i = ig * 32 + wv * 8 + ii;
        const __half* up = U16 + ((size_t)b * CI + i) * JM + l * 32;

        union { float4 f; __half2 h2[4]; } r[4];
        r[0].f = *(const float4*)(up);
        r[1].f = *(const float4*)(up + 8);
        r[2].f = *(const float4*)(up + 16);
        r[3].f = *(const float4*)(up + 24);

        // agreement: ap = sum_m v[b,j,m] * u[b,i,j,m]
        float ap = 0.0f;
#pragma unroll
        for (int q = 0; q < 4; ++q)
#pragma unroll
            for (int p = 0; p < 4; ++p) {
                const float2 w2 = __half22float2(r[q].h2[p]);
                const int m = q * 8 + p * 2;
                ap = fmaf(vT[m * 64 + l], w2.x, ap);
                ap = fmaf(vT[(m + 1) * 64 + l], w2.y, ap);
            }

        float L = ap;
        if (PASS == 2)
            L += a0[((size_t)b * CI + i) * CJ + l];
        if (PASS == 1)
            a0[((size_t)b * CI + i) * CJ + l] = ap;

        // softmax over 64 j (whole wave)
        float mx = L;
#pragma unroll
        for (int d = 1; d < 64; d <<= 1)
            mx = fmaxf(mx, __shfl_xor(mx, d));
        const float e = __expf(ALPHA * (L - mx));
        float se = e;
#pragma unroll
        for (int d = 1; d < 64; d <<= 1)
            se += __shfl_xor(se, d);
        const float c = e * (64.0f / se);

#pragma unroll
        for (int q = 0; q < 4; ++q)
#pragma unroll
            for (int p = 0; p < 4; ++p) {
                const float2 w2 = __half22float2(r[q].h2[p]);
                const int m = q * 8 + p * 2;
                acc[m]     = fmaf(c, w2.x, acc[m]);
                acc[m + 1] = fmaf(c, w2.y, acc[m + 1]);
            }
    }

    // PART[b][p][jm], p = ig*4 + wv ; lane writes its 32 m's (j = l)
    float* dst = part + ((size_t)b * NCH + (ig * 4 + wv)) * JM + l * 32;
#pragma unroll
    for (int q = 0; q < 8; ++q)
        *(float4*)(dst + q * 4) =
            make_float4(acc[q * 4], acc[q * 4 + 1], acc[q * 4 + 2], acc[q * 4 + 3]);
}

// ---------------------------------------------------------------------------
// reduce PART[b][p][jm] over p (256) + squash.
// ---------------------------------------------------------------------------
__global__ __launch_bounds__(1024)
void reduce_squash(const float* __restrict__ part, float* __restrict__ v)
{
    __shared__ float red[4][256];
    const int tid = threadIdx.x;
    const int seg = tid >> 8;
    const int loc = tid & 255;
    const int b   = blockIdx.x >> 3;
    const int jmb = (blockIdx.x & 7) * 256;

    const float* p = part + ((size_t)b * NCH + seg * 64) * JM + jmb + loc;
    float s0 = 0.f, s1 = 0.f, s2 = 0.f, s3 = 0.f;
#pragma unroll 4
    for (int q = 0; q < 64; q += 4) {
        s0 += p[(size_t)(q + 0) * JM];
        s1 += p[(size_t)(q + 1) * JM];
        s2 += p[(size_t)(q + 2) * JM];
        s3 += p[(size_t)(q + 3) * JM];
    }
    red[seg][loc] = (s0 + s1) + (s2 + s3);
    __syncthreads();

    if (tid < 256) {
        const float s = (red[0][loc] + red[1][loc]) + (red[2][loc] + red[3][loc]);
        float sq = s * s;
#pragma unroll
        for (int k = 1; k < 32; k <<= 1) sq += __shfl_xor(sq, k);
        v[(size_t)b * JM + jmb + loc] =
            (sq / (1.0f + sq)) * (s * rsqrtf(sq + 1e-7f));
    }
}

__global__ __launch_bounds__(256)
void squash_kernel(const float* __restrict__ s, float* __restrict__ v)
{
    const int g = blockIdx.x * 256 + threadIdx.x;
    const float val = s[g];
    float sq = val * val;
#pragma unroll
    for (int k = 1; k < 32; k <<= 1) sq += __shfl_xor(sq, k);
    v[g] = (sq / (1.0f + sq)) * (val * rsqrtf(sq + 1e-7f));
}

// ---------------------------------------------------------------------------
extern "C" void kernel_launch(void* const* d_in, const int* in_sizes, int n_in,
                              void* d_out, int out_size, void* d_ws, size_t ws_size,
                              hipStream_t stream)
{
    const float* x = (const float*)d_in[0];
    const float* w = (const float*)d_in[1];
    float* out = (float*)d_out;
    float* ws  = (float*)d_ws;

    float* A0   = ws;                                   // 2,097,152 f
    float* V0   = A0 + (size_t)B_ * CI * CJ;            // 32768 f
    float* V1   = V0 + (size_t)B_ * JM;                 // 32768 f
    float* PART = V1 + (size_t)B_ * JM;                 // 8,388,608 f
    __half* U16 = (__half*)(PART + (size_t)B_ * NCH * JM);  // 134 MB fp16

    const size_t need_part =
        ((size_t)B_ * CI * CJ + 2 * (size_t)B_ * JM
         + (size_t)B_ * NCH * JM) * sizeof(float);      // ~42.6 MB
    const size_t need_full =
        need_part + (size_t)B_ * CI * JM * sizeof(__half);  // ~176.5 MB

    if (ws_size >= need_full) {
        pass_kernel<0, false, true><<<512, 1024, 0, stream>>>(x, w, nullptr, nullptr, PART, U16);
        reduce_squash<<<128, 1024, 0, stream>>>(PART, V0);
        route_kernel<1><<<1024, 256, 0, stream>>>(U16, V0, A0, PART);
        reduce_squash<<<128, 1024, 0, stream>>>(PART, V1);
        route_kernel<2><<<1024, 256, 0, stream>>>(U16, V1, A0, PART);
        reduce_squash<<<128, 1024, 0, stream>>>(PART, out);
    } else if (ws_size >= need_part) {
        pass_kernel<0, false, false><<<512, 1024, 0, stream>>>(x, w, nullptr, nullptr, PART, nullptr);
        reduce_squash<<<128, 1024, 0, stream>>>(PART, V0);
        pass_kernel<1, false, false><<<512, 1024, 0, stream>>>(x, w, V0, A0, PART, nullptr);
        reduce_squash<<<128, 1024, 0, stream>>>(PART, V1);
        pass_kernel<2, false, false><<<512, 1024, 0, stream>>>(x, w, V1, A0, PART, nullptr);
        reduce_squash<<<128, 1024, 0, stream>>>(PART, out);
    } else {
        float* S0 = V1 + (size_t)B_ * JM;
        float* S1 = S0 + (size_t)B_ * JM;
        float* S2 = S1 + (size_t)B_ * JM;
        hipMemsetAsync(S0, 0, (size_t)3 * B_ * JM * sizeof(float), stream);
        pass_kernel<0, true, false><<<512, 1024, 0, stream>>>(x, w, nullptr, nullptr, S0, nullptr);
        squash_kernel<<<128, 256, 0, stream>>>(S0, V0);
        pass_kernel<1, true, false><<<512, 1024, 0, stream>>>(x, w, V0, A0, S1, nullptr);
        squash_kernel<<<128, 256, 0, stream>>>(S1, V1);
        pass_kernel<2, true, false><<<512, 1024, 0, stream>>>(x, w, V1, A0, S2, nullptr);
        squash_kernel<<<128, 256, 0, stream>>>(S2, out);
    }
}